// Round 1
// baseline (144.671 us; speedup 1.0000x reference)
//
#include <hip/hip_runtime.h>
#include <hip/hip_bf16.h>
#include <cstdint>

// Problem constants: B=4, N=256, D=128, HID=128, IN_DIM=516.
// Decomposition:
//   pre(p=(i,j), h) = [ |h_i-h_j| ; h_i*h_j ] @ W1[256:512]   (MFMA GEMM, K=256)
//                   + Pi[b,i,h] + Pj[b,j,h] + b1[h]           (precomputed / epilogue)
//                   + base*w512 + sig(base)*w513 + comp*w514 + sig(comp)*w515
//   logit = relu(pre) @ W2 + b2 ; symmetrize ; diag = -1e9

typedef float f32x4 __attribute__((ext_vector_type(4)));
typedef short s16x8 __attribute__((ext_vector_type(8)));

#define LDK 264  // padded K-row length in ushort (256 + 8) -> 528B row stride, bank-rotated

__device__ __forceinline__ uint32_t pack_bf16_2(float a, float b) {
  uint32_t ua = __builtin_bit_cast(uint32_t, a);
  uint32_t ub = __builtin_bit_cast(uint32_t, b);
  ua += 0x7FFFu + ((ua >> 16) & 1u);  // RNE
  ub += 0x7FFFu + ((ub >> 16) & 1u);
  return (ua >> 16) | (ub & 0xFFFF0000u);
}

// ---- Kernel 1: pack W1 rows 256..511 as bf16, transposed [h][k] (k contiguous) ----
__global__ __launch_bounds__(128) void pack_w1(const float* __restrict__ W1,
                                               unsigned short* __restrict__ W1pT) {
  int k = blockIdx.x;    // 0..255
  int h = threadIdx.x;   // 0..127
  float v = W1[(256 + k) * 128 + h];  // rows 256..511 = diff then prod weights
  uint32_t u = __builtin_bit_cast(uint32_t, v);
  u += 0x7FFFu + ((u >> 16) & 1u);
  W1pT[h * 256 + k] = (unsigned short)(u >> 16);
}

// ---- Kernel 2: Pi[row,h] = node[row,:] @ W1[0:128,:],  Pj = node @ W1[128:256,:] ----
__global__ __launch_bounds__(128) void pipj_k(const float* __restrict__ node,
                                              const float* __restrict__ W1,
                                              float* __restrict__ Pi,
                                              float* __restrict__ Pj) {
  __shared__ float sN[128];
  int row = blockIdx.x;   // b*256 + n, 1024 rows
  int h = threadIdx.x;
  sN[h] = node[row * 128 + h];
  __syncthreads();
  float ai = 0.f, aj = 0.f;
#pragma unroll 8
  for (int d = 0; d < 128; ++d) {
    float v = sN[d];
    ai = fmaf(v, W1[d * 128 + h], ai);
    aj = fmaf(v, W1[(128 + d) * 128 + h], aj);
  }
  Pi[row * 128 + h] = ai;
  Pj[row * 128 + h] = aj;
}

// ---- Kernel 3: main fused pair-MLP GEMM ----
// grid: 2048 = b(4) * i(256) * jt(2). Tile: 128 pairs (one i, 128 j) x 128 hidden.
__global__ __launch_bounds__(256) void main_k(
    const float* __restrict__ node, const float* __restrict__ baseL,
    const float* __restrict__ compL, const float* __restrict__ W1,
    const float* __restrict__ b1, const float* __restrict__ W2,
    const float* __restrict__ b2, const unsigned short* __restrict__ W1pT,
    const float* __restrict__ Pi, const float* __restrict__ Pj,
    float* __restrict__ L) {
  __shared__ unsigned short sF[128 * LDK];  // 67584 B: [pair p][k] bf16 features
  __shared__ float sHi[128];
  __shared__ float sCi[128];     // Pi[b,i,:] + b1
  __shared__ float sW2[128];
  __shared__ float sW[4][128];   // W1 rows 512..515 (base, sig(base), comp, sig(comp))
  __shared__ float sScal[128][4];
  __shared__ float outp[128][2];

  const int tid = threadIdx.x;
  const int bx = blockIdx.x;
  const int jt = bx & 1;
  const int i = (bx >> 1) & 255;
  const int b = bx >> 9;
  const int j0 = jt * 128;
  const int rowI = b * 256 + i;

  // ---- stage per-WG tables ----
  if (tid < 128) {
    sHi[tid] = node[rowI * 128 + tid];
    sCi[tid] = Pi[rowI * 128 + tid] + b1[tid];
    sW2[tid] = W2[tid];
    float bl = baseL[rowI * 256 + j0 + tid];
    bl = fminf(fmaxf(bl, -20.f), 20.f);
    float cl = compL[rowI * 256 + j0 + tid];
    cl = fminf(fmaxf(cl, -20.f), 20.f);
    sScal[tid][0] = bl;
    sScal[tid][1] = 1.f / (1.f + __expf(-bl));
    sScal[tid][2] = cl;
    sScal[tid][3] = 1.f / (1.f + __expf(-cl));
  }
  {
    int c = tid >> 7, h = tid & 127;   // 256 threads cover c=0,1; second pass c+2
    sW[c][h] = W1[(512 + c) * 128 + h];
    sW[c + 2][h] = W1[(514 + c) * 128 + h];
  }
  __syncthreads();

  // ---- build feature tile: k<128 -> |hi-hj|, k>=128 -> hi*hj ----
#pragma unroll
  for (int it = 0; it < 16; ++it) {
    int slot = it * 256 + tid;
    int j = slot >> 5;    // 32 float4 per 128-d row
    int d4 = slot & 31;
    const float4 hj = *reinterpret_cast<const float4*>(node + (b * 256 + j0 + j) * 128 + d4 * 4);
    const float4 hi = *reinterpret_cast<const float4*>(&sHi[d4 * 4]);
    uint32_t dlo = pack_bf16_2(fabsf(hi.x - hj.x), fabsf(hi.y - hj.y));
    uint32_t dhi = pack_bf16_2(fabsf(hi.z - hj.z), fabsf(hi.w - hj.w));
    uint32_t plo = pack_bf16_2(hi.x * hj.x, hi.y * hj.y);
    uint32_t phi = pack_bf16_2(hi.z * hj.z, hi.w * hj.w);
    *reinterpret_cast<uint2*>(&sF[j * LDK + d4 * 4]) = make_uint2(dlo, dhi);
    *reinterpret_cast<uint2*>(&sF[j * LDK + 128 + d4 * 4]) = make_uint2(plo, phi);
  }
  __syncthreads();

  // ---- MFMA main loop: D[p][h] += F[p][k] * W1cd[k][h], K=256 in 8 steps ----
  const int lane = tid & 63;
  const int wave = tid >> 6;
  const int wm = wave >> 1, wn = wave & 1;
  const int col = lane & 15, quad = lane >> 4;

  f32x4 acc[4][4] = {};

  const unsigned short* sFbase = &sF[(wm * 64 + col) * LDK + quad * 8];
  const unsigned short* wbase = W1pT + (wn * 64 + col) * 256 + quad * 8;

#pragma unroll
  for (int ks = 0; ks < 8; ++ks) {
    s16x8 bfrag[4], afrag[4];
#pragma unroll
    for (int ni = 0; ni < 4; ++ni)
      bfrag[ni] = *reinterpret_cast<const s16x8*>(wbase + ni * 16 * 256 + ks * 32);
#pragma unroll
    for (int mi = 0; mi < 4; ++mi)
      afrag[mi] = *reinterpret_cast<const s16x8*>(sFbase + mi * 16 * LDK + ks * 32);
#pragma unroll
    for (int mi = 0; mi < 4; ++mi)
#pragma unroll
      for (int ni = 0; ni < 4; ++ni)
        acc[mi][ni] = __builtin_amdgcn_mfma_f32_16x16x32_bf16(afrag[mi], bfrag[ni],
                                                              acc[mi][ni], 0, 0, 0);
  }

  // ---- epilogue: add per-i/per-j/scalar terms, relu, dot W2, reduce over h ----
  float cCi[4], cW2v[4], cB0[4], cB1[4], cB2[4], cB3[4];
  const int hbase = wn * 64 + col;
#pragma unroll
  for (int ni = 0; ni < 4; ++ni) {
    int h = hbase + ni * 16;
    cCi[ni] = sCi[h];
    cW2v[ni] = sW2[h];
    cB0[ni] = sW[0][h]; cB1[ni] = sW[1][h]; cB2[ni] = sW[2][h]; cB3[ni] = sW[3][h];
  }
  const float b2v = b2[0];

#pragma unroll
  for (int mi = 0; mi < 4; ++mi) {
#pragma unroll
    for (int r = 0; r < 4; ++r) {
      int p = wm * 64 + mi * 16 + quad * 4 + r;   // C/D layout: row = quad*4+reg
      const float* pjrow = Pj + (b * 256 + j0 + p) * 128 + hbase;
      float s0 = sScal[p][0], s1 = sScal[p][1], s2 = sScal[p][2], s3 = sScal[p][3];
      float sum = 0.f;
#pragma unroll
      for (int ni = 0; ni < 4; ++ni) {
        float pre = acc[mi][ni][r] + cCi[ni] + pjrow[ni * 16]
                  + s0 * cB0[ni] + s1 * cB1[ni] + s2 * cB2[ni] + s3 * cB3[ni];
        sum += fmaxf(pre, 0.f) * cW2v[ni];
      }
      sum += __shfl_xor(sum, 1);
      sum += __shfl_xor(sum, 2);
      sum += __shfl_xor(sum, 4);
      sum += __shfl_xor(sum, 8);   // sum over 16 cols (h) within quad-group
      if (col == 0) outp[p][wn] = sum;
    }
  }
  __syncthreads();
  if (tid < 128) {
    L[rowI * 256 + j0 + tid] = outp[tid][0] + outp[tid][1] + b2v;
  }
}

// ---- Kernel 4: symmetrize + diagonal ----
__global__ __launch_bounds__(256) void sym_k(const float* __restrict__ L,
                                             float* __restrict__ out) {
  int idx = blockIdx.x * 256 + threadIdx.x;   // 262144 total
  int b = idx >> 16;
  int i = (idx >> 8) & 255;
  int j = idx & 255;
  float v;
  if (i == j) {
    v = -1e9f;
  } else {
    v = 0.5f * (L[idx] + L[(b << 16) | (j << 8) | i]);
  }
  out[idx] = v;
}

extern "C" void kernel_launch(void* const* d_in, const int* in_sizes, int n_in,
                              void* d_out, int out_size, void* d_ws, size_t ws_size,
                              hipStream_t stream) {
  const float* node = (const float*)d_in[0];   // [4,256,128]
  const float* baseL = (const float*)d_in[1];  // [4,256,256]
  const float* compL = (const float*)d_in[2];  // [4,256,256]
  const float* W1 = (const float*)d_in[3];     // [516,128]
  const float* b1 = (const float*)d_in[4];     // [128]
  const float* W2 = (const float*)d_in[5];     // [128,1]
  const float* b2 = (const float*)d_in[6];     // [1]
  float* out = (float*)d_out;                  // [4,256,256] fp32

  char* ws = (char*)d_ws;
  float* Pi = (float*)(ws);                              // 512 KB
  float* Pj = (float*)(ws + (512 << 10));                // 512 KB
  unsigned short* W1pT = (unsigned short*)(ws + (1024 << 10));  // 64 KB
  float* L = (float*)(ws + (1088 << 10));                // 1 MB

  pack_w1<<<256, 128, 0, stream>>>(W1, W1pT);
  pipj_k<<<1024, 128, 0, stream>>>(node, W1, Pi, Pj);
  main_k<<<2048, 256, 0, stream>>>(node, baseL, compL, W1, b1, W2, b2, W1pT, Pi, Pj, L);
  sym_k<<<1024, 256, 0, stream>>>(L, out);
}

// Round 2
// 116.018 us; speedup vs baseline: 1.2470x; 1.2470x over previous
//
#include <hip/hip_runtime.h>
#include <cstdint>

// B=4, N=256, D=128, HID=128.
// pre(p=(i,j),h) = [ |hi-hj| ; hi*hj ; hj ] @ Wcat  (K=384 bf16 MFMA GEMM)
//                + (Pi[i,h]+b1[h]) + base*w512 + sig(base)*w513 + comp*w514 + sig(comp)*w515
// logit = relu(pre)@W2 + b2 ; symmetrize ; diag=-1e9
// Wcat row map: k<256 -> W1 row 256+k (diff,prod) ; k>=256 -> W1 row k-128 (hj block).

typedef float f32x4 __attribute__((ext_vector_type(4)));
typedef short s16x8 __attribute__((ext_vector_type(8)));

#define LDK 392  // 384 + 8 pad ushorts -> 784B row = 49*16B (odd) -> 2-way-free b128 reads

__device__ __forceinline__ uint32_t pkt(float lo, float hi) {
  uint32_t l = __builtin_bit_cast(uint32_t, lo);
  uint32_t h = __builtin_bit_cast(uint32_t, hi);
  return (l >> 16) | (h & 0xffff0000u);  // bf16 truncate-pack (lshr+bfi)
}

// blocks [0,48): pack W1f in MFMA-B-fragment order (16B/lane coalesced loads in main_k)
// blocks [48,1072): PiB[row,h] = node[row,:] @ W1[0:128,:] + b1[h]
__global__ __launch_bounds__(128) void pre_k(const float* __restrict__ node,
                                             const float* __restrict__ W1,
                                             const float* __restrict__ b1,
                                             unsigned short* __restrict__ W1f,
                                             float* __restrict__ PiB) {
  int bid = blockIdx.x;
  if (bid < 48) {
    int idx = bid * 128 + threadIdx.x;  // (ks*8 + h16)*64 + lane, 6144 total
    int lane = idx & 63;
    int h16 = (idx >> 6) & 7;
    int ks = idx >> 9;
    int col = lane & 15, quad = lane >> 4;
    int h = h16 * 16 + col;
    uint32_t w[4];
#pragma unroll
    for (int rp = 0; rp < 4; ++rp) {
      int k0 = ks * 32 + quad * 8 + rp * 2;
      int s0 = (k0 < 256) ? 256 + k0 : k0 - 128;  // k0,k0+1 -> s0,s0+1 (same region)
      w[rp] = pkt(W1[s0 * 128 + h], W1[(s0 + 1) * 128 + h]);
    }
    *reinterpret_cast<uint4*>(W1f + (size_t)idx * 8) = *reinterpret_cast<const uint4*>(w);
  } else {
    __shared__ float sN[128];
    int row = bid - 48;  // 0..1023
    int h = threadIdx.x;
    sN[h] = node[row * 128 + h];
    __syncthreads();
    float ai = 0.f;
#pragma unroll 8
    for (int d = 0; d < 128; ++d) ai = fmaf(sN[d], W1[d * 128 + h], ai);
    PiB[row * 128 + h] = ai + b1[h];
  }
}

// grid 4096 = b(4) * i(256) * jt(4). Tile: 64 pairs (one i, 64 j) x 128 hidden, K=384.
__global__ __launch_bounds__(256, 3) void main_k(
    const float* __restrict__ node, const float* __restrict__ baseL,
    const float* __restrict__ compL, const float* __restrict__ W1,
    const float* __restrict__ W2, const float* __restrict__ b2,
    const unsigned short* __restrict__ W1f, const float* __restrict__ PiB,
    float* __restrict__ L) {
  __shared__ __align__(16) unsigned short sF[64 * LDK];  // 50176 B, reused as sPart
  __shared__ float sHi[128];
  __shared__ float sScal[64][4];

  const int tid = threadIdx.x;
  const int bx = blockIdx.x;
  const int jt = bx & 3;
  const int i = (bx >> 2) & 255;
  const int b = bx >> 10;
  const int j0 = jt * 64;
  const int rowI = b * 256 + i;

  const int lane = tid & 63;
  const int wave = tid >> 6;
  const int wm = wave >> 1, wn = wave & 1;
  const int col = lane & 15, quad = lane >> 4;

  // epilogue-constant preloads (global, L2-hot; independent of everything below)
  float cCi[4], cW2[4], cB0[4], cB1[4], cB2[4], cB3[4];
#pragma unroll
  for (int ni = 0; ni < 4; ++ni) {
    int h = wn * 64 + ni * 16 + col;
    cCi[ni] = PiB[rowI * 128 + h];
    cW2[ni] = W2[h];
    cB0[ni] = W1[512 * 128 + h];
    cB1[ni] = W1[513 * 128 + h];
    cB2[ni] = W1[514 * 128 + h];
    cB3[ni] = W1[515 * 128 + h];
  }
  const float b2v = b2[0];

  if (tid < 128) sHi[tid] = node[rowI * 128 + tid];
  if (tid < 64) {
    float bl = baseL[rowI * 256 + j0 + tid];
    bl = fminf(fmaxf(bl, -20.f), 20.f);
    float cl = compL[rowI * 256 + j0 + tid];
    cl = fminf(fmaxf(cl, -20.f), 20.f);
    sScal[tid][0] = bl;
    sScal[tid][1] = 1.f / (1.f + __expf(-bl));
    sScal[tid][2] = cl;
    sScal[tid][3] = 1.f / (1.f + __expf(-cl));
  }
  __syncthreads();

  // ---- build F tile: [64 pairs][384 k] bf16: |diff|(128) | prod(128) | hj(128) ----
  {
    const int d4 = tid & 31;  // float4 index within 128-d
    const int r0 = tid >> 5;  // 0..7
    const float4 hi = *reinterpret_cast<const float4*>(&sHi[d4 * 4]);
#pragma unroll
    for (int it = 0; it < 8; ++it) {
      int j = it * 8 + r0;
      const float4 hj =
          *reinterpret_cast<const float4*>(node + (size_t)(b * 256 + j0 + j) * 128 + d4 * 4);
      uint2 dd, pp, jj;
      dd.x = pkt(fabsf(hi.x - hj.x), fabsf(hi.y - hj.y));
      dd.y = pkt(fabsf(hi.z - hj.z), fabsf(hi.w - hj.w));
      pp.x = pkt(hi.x * hj.x, hi.y * hj.y);
      pp.y = pkt(hi.z * hj.z, hi.w * hj.w);
      jj.x = pkt(hj.x, hj.y);
      jj.y = pkt(hj.z, hj.w);
      *reinterpret_cast<uint2*>(&sF[j * LDK + d4 * 4]) = dd;
      *reinterpret_cast<uint2*>(&sF[j * LDK + 128 + d4 * 4]) = pp;
      *reinterpret_cast<uint2*>(&sF[j * LDK + 256 + d4 * 4]) = jj;
    }
  }
  __syncthreads();

  // ---- MFMA: C[64 pairs][128 h] = F[64][384] @ Wcat[384][128] ----
  f32x4 acc[2][4] = {};
  const unsigned short* aptr = &sF[(wm * 32 + col) * LDK + quad * 8];
#pragma unroll
  for (int ks = 0; ks < 12; ++ks) {
    s16x8 bfrag[4], afrag[2];
#pragma unroll
    for (int ni = 0; ni < 4; ++ni)
      bfrag[ni] = *reinterpret_cast<const s16x8*>(
          W1f + (size_t)((ks * 8 + wn * 4 + ni) * 64 + lane) * 8);
#pragma unroll
    for (int mi = 0; mi < 2; ++mi)
      afrag[mi] = *reinterpret_cast<const s16x8*>(aptr + mi * 16 * LDK + ks * 32);
#pragma unroll
    for (int mi = 0; mi < 2; ++mi)
#pragma unroll
      for (int ni = 0; ni < 4; ++ni)
        acc[mi][ni] =
            __builtin_amdgcn_mfma_f32_16x16x32_bf16(afrag[mi], bfrag[ni], acc[mi][ni], 0, 0, 0);
  }

  __syncthreads();  // all A-frag reads done; reuse sF as partial-sum buffer
  float(*sPart)[36] = reinterpret_cast<float(*)[36]>(sF);  // 64 x 36 floats (144B row, 9*16B)

  // ---- epilogue: add per-i + scalar terms, relu, dot W2 -> per-lane partial ----
#pragma unroll
  for (int mi = 0; mi < 2; ++mi) {
#pragma unroll
    for (int r = 0; r < 4; ++r) {
      int p = wm * 32 + mi * 16 + quad * 4 + r;  // C/D: row = quad*4 + reg
      float s0 = sScal[p][0], s1 = sScal[p][1], s2 = sScal[p][2], s3 = sScal[p][3];
      float val = 0.f;
#pragma unroll
      for (int ni = 0; ni < 4; ++ni) {
        float pre = acc[mi][ni][r] + cCi[ni] + s0 * cB0[ni] + s1 * cB1[ni] + s2 * cB2[ni] +
                    s3 * cB3[ni];
        val = fmaf(fmaxf(pre, 0.f), cW2[ni], val);
      }
      sPart[p][wn * 16 + col] = val;  // 32 partials per pair (over h groups)
    }
  }
  __syncthreads();
  if (tid < 64) {
    const f32x4* row = reinterpret_cast<const f32x4*>(&sPart[tid][0]);
    f32x4 a4 = row[0];
#pragma unroll
    for (int c = 1; c < 8; ++c) a4 += row[c];
    L[rowI * 256 + j0 + tid] = a4.x + a4.y + a4.z + a4.w + b2v;
  }
}

__global__ __launch_bounds__(256) void sym_k(const float* __restrict__ L,
                                             float* __restrict__ out) {
  int idx = blockIdx.x * 256 + threadIdx.x;  // 262144
  int b = idx >> 16;
  int i = (idx >> 8) & 255;
  int j = idx & 255;
  float v;
  if (i == j) {
    v = -1e9f;
  } else {
    v = 0.5f * (L[idx] + L[(b << 16) | (j << 8) | i]);
  }
  out[idx] = v;
}

extern "C" void kernel_launch(void* const* d_in, const int* in_sizes, int n_in,
                              void* d_out, int out_size, void* d_ws, size_t ws_size,
                              hipStream_t stream) {
  const float* node = (const float*)d_in[0];   // [4,256,128]
  const float* baseL = (const float*)d_in[1];  // [4,256,256]
  const float* compL = (const float*)d_in[2];  // [4,256,256]
  const float* W1 = (const float*)d_in[3];     // [516,128]
  const float* b1 = (const float*)d_in[4];     // [128]
  const float* W2 = (const float*)d_in[5];     // [128,1]
  const float* b2 = (const float*)d_in[6];     // [1]
  float* out = (float*)d_out;                  // [4,256,256] fp32

  char* ws = (char*)d_ws;
  float* PiB = (float*)(ws);                                 // 512 KB
  unsigned short* W1f = (unsigned short*)(ws + (512 << 10)); // 96 KB
  float* L = (float*)(ws + (1 << 20));                       // 1 MB

  pre_k<<<1072, 128, 0, stream>>>(node, W1, b1, W1f, PiB);
  main_k<<<4096, 256, 0, stream>>>(node, baseL, compL, W1, W2, b2, W1f, PiB, L);
  sym_k<<<1024, 256, 0, stream>>>(L, out);
}

// Round 4
// 105.305 us; speedup vs baseline: 1.3738x; 1.1017x over previous
//
#include <hip/hip_runtime.h>
#include <cstdint>

// B=4, N=256, D=128, HID=128, IN_DIM=516.
// pre(p=(i,j),h) = [|hi-hj| ; hi*hj] @ W1[256:512]        (K=256 fp8 MFMA GEMM, W x256)
//                + PiB[i,h] + Pj[j,h]                      (precomputed fp32/bf16)
//                + base*w512 + sig(base)*w513 + comp*w514 + sig(comp)*w515
// logit = relu(pre)@W2 + b2 ; out[i,j] += 0.5*logit, out[j,i] += 0.5*logit ; diag=-1e9.
// W1 rows: 0-127 hi | 128-255 hj | 256-383 |diff| | 384-511 prod | 512-515 scalars.

typedef float f32x4 __attribute__((ext_vector_type(4)));

#define INV256 0.00390625f

__device__ __forceinline__ uint32_t pk4(float a, float b, float c, float d) {
  uint32_t u = __builtin_amdgcn_cvt_pk_fp8_f32(a, b, 0, false);
  u = __builtin_amdgcn_cvt_pk_fp8_f32(c, d, u, true);
  return u;
}
__device__ __forceinline__ float bf2f(unsigned short u) {
  uint32_t x = ((uint32_t)u) << 16;
  return __builtin_bit_cast(float, x);
}
__device__ __forceinline__ long mk64(uint32_t lo, uint32_t hi) {
  return (long)((((unsigned long long)hi) << 32) | lo);
}

// bid<32: pack fp8 B-image (lane-linear MFMA fragment order, values W1*256)
// bid in [32,1056): PiB = node@W1[0:128] + b1 (fp32); Pjh = node@W1[128:256] (bf16)
// bid in [1056,2080): zero out + diag -1e9 (ALL 1024 (b,i) rows — R3 bug: only 256)
__global__ __launch_bounds__(128) void pre_k(const float* __restrict__ node,
                                             const float* __restrict__ W1,
                                             const float* __restrict__ b1,
                                             float* __restrict__ PiB,
                                             unsigned short* __restrict__ Pjh,
                                             uint32_t* __restrict__ W1f8,
                                             float* __restrict__ out) {
  int bid = blockIdx.x;
  int tid = threadIdx.x;
  if (bid < 32) {
    // bid = ks*4 + nip*2 + wn ; thread: lane=tid&63, nilow=tid>>6
    int ks = bid >> 2, nip = (bid >> 1) & 1, wn = bid & 1;
    int lane = tid & 63, nilow = tid >> 6;
    int quad = lane >> 4, col = lane & 15;
    int h = wn * 64 + (nip * 2 + nilow) * 16 + col;
    int k0 = ks * 32 + quad * 8;
    float w[8];
#pragma unroll
    for (int t = 0; t < 8; ++t) w[t] = W1[(256 + k0 + t) * 128 + h] * 256.0f;
    uint2 u;
    u.x = pk4(w[0], w[1], w[2], w[3]);
    u.y = pk4(w[4], w[5], w[6], w[7]);
    // byte offset = (bid*64 + lane)*16 + nilow*8
    reinterpret_cast<uint2*>(W1f8)[(bid * 64 + lane) * 2 + nilow] = u;
  } else if (bid < 1056) {
    __shared__ float sN[128];
    int row = bid - 32;  // 0..1023
    int h = tid;
    sN[h] = node[row * 128 + h];
    __syncthreads();
    float ai = 0.f, aj = 0.f;
#pragma unroll 8
    for (int d = 0; d < 128; ++d) {
      float v = sN[d];
      ai = fmaf(v, W1[d * 128 + h], ai);
      aj = fmaf(v, W1[(128 + d) * 128 + h], aj);
    }
    PiB[row * 128 + h] = ai + b1[h];
    Pjh[row * 128 + h] = (unsigned short)(__builtin_bit_cast(uint32_t, aj) >> 16);
  } else {
    int r = bid - 1056;  // (b,i) row, 0..1023
    int i = r & 255;
    out[r * 256 + tid] = (tid == i) ? -1e9f : 0.0f;
    out[r * 256 + 128 + tid] = (tid + 128 == i) ? -1e9f : 0.0f;
  }
}

// grid 4096 = b(4)*i(256)*jt(4). Tile: 64 pairs (one i, 64 j) x 128 h, K=256 fp8.
__global__ __launch_bounds__(256, 3) void main_k(
    const float* __restrict__ node, const float* __restrict__ baseL,
    const float* __restrict__ compL, const float* __restrict__ W1,
    const float* __restrict__ W2, const float* __restrict__ b2,
    const uint32_t* __restrict__ W1f8, const float* __restrict__ PiB,
    const unsigned short* __restrict__ Pjh, float* __restrict__ out) {
  // sF image: [ks 0..7](2080B){ [wm 0..1][lane 0..63](16B){ [mi 0..1] 8 fp8 } } = 16640 B
  // sB image: [ks 0..7][nip 0..1][wn 0..1][lane 0..63] 16B = 32768 B
  __shared__ __align__(16) char smem[16640 + 32768];
  __shared__ float sHi[128];
  __shared__ float sScal[64][4];
  char* sF = smem;
  char* sB = smem + 16640;

  const int tid = threadIdx.x;
  const int bx = blockIdx.x;
  const int jt = bx & 3;
  const int i = (bx >> 2) & 255;
  const int b = bx >> 10;
  const int j0 = jt * 64;
  const int rowI = b * 256 + i;
  const int jbase = b * 256 + j0;

  const int lane = tid & 63;
  const int wave = tid >> 6;
  const int wm = wave >> 1, wn = wave & 1;
  const int col = lane & 15, quad = lane >> 4;

  // ---- B stage to registers (latency overlapped with everything below) ----
  uint4 g[8];
#pragma unroll
  for (int it = 0; it < 8; ++it)
    g[it] = reinterpret_cast<const uint4*>(W1f8)[it * 256 + tid];

  // ---- early Pj loads (consumed only in epilogue; huge latency tolerance) ----
  float pj[2][4][4];
#pragma unroll
  for (int mi = 0; mi < 2; ++mi)
#pragma unroll
    for (int r = 0; r < 4; ++r) {
      int p = wm * 32 + mi * 16 + quad * 4 + r;
      const unsigned short* row = Pjh + (size_t)(jbase + p) * 128 + wn * 64 + col;
#pragma unroll
      for (int ni = 0; ni < 4; ++ni) pj[mi][r][ni] = bf2f(row[ni * 16]);
    }

  // ---- epilogue constants (per-h for this lane's 4 ni columns) ----
  float cCi[4], cW2[4], cB0[4], cB1[4], cB2[4], cB3[4];
#pragma unroll
  for (int ni = 0; ni < 4; ++ni) {
    int h = wn * 64 + ni * 16 + col;
    cCi[ni] = PiB[rowI * 128 + h];
    cW2[ni] = W2[h];
    cB0[ni] = W1[512 * 128 + h];
    cB1[ni] = W1[513 * 128 + h];
    cB2[ni] = W1[514 * 128 + h];
    cB3[ni] = W1[515 * 128 + h];
  }
  const float b2v = b2[0];

  if (tid < 128) sHi[tid] = node[rowI * 128 + tid];
  if (tid < 64) {
    float bl = fminf(fmaxf(baseL[rowI * 256 + j0 + tid], -20.f), 20.f);
    float cl = fminf(fmaxf(compL[rowI * 256 + j0 + tid], -20.f), 20.f);
    sScal[tid][0] = bl;
    sScal[tid][1] = 1.f / (1.f + __expf(-bl));
    sScal[tid][2] = cl;
    sScal[tid][3] = 1.f / (1.f + __expf(-cl));
  }
  // commit B image to LDS
#pragma unroll
  for (int it = 0; it < 8; ++it)
    reinterpret_cast<uint4*>(sB)[it * 256 + tid] = g[it];
  __syncthreads();

  // ---- F-build: 64 pairs x 256 k fp8, written directly in A-fragment order ----
  {
    const int d4 = tid & 31;   // float4 index in 128 dims
    const int r = tid >> 5;    // 0..7
    const float4 hi = *reinterpret_cast<const float4*>(&sHi[d4 * 4]);
    const int ks1 = d4 >> 3;             // diff ks 0..3
    const int qj = (d4 >> 1) & 3;        // quad of k-group
    const int kb = (d4 & 1) * 4;         // byte offset within 8B group
#pragma unroll
    for (int pass = 0; pass < 8; ++pass) {
      int j = pass * 8 + r;
      const float4 hj =
          *reinterpret_cast<const float4*>(node + (size_t)(jbase + j) * 128 + d4 * 4);
      uint32_t du = pk4(fabsf(hi.x - hj.x), fabsf(hi.y - hj.y),
                        fabsf(hi.z - hj.z), fabsf(hi.w - hj.w));
      uint32_t pu = pk4(hi.x * hj.x, hi.y * hj.y, hi.z * hj.z, hi.w * hj.w);
      int colj = j & 15, m16 = j >> 4;
      int off = (m16 >> 1) * 1024 + (qj * 16 + colj) * 16 + (m16 & 1) * 8 + kb;
      *reinterpret_cast<uint32_t*>(sF + ks1 * 2080 + off) = du;
      *reinterpret_cast<uint32_t*>(sF + (4 + ks1) * 2080 + off) = pu;
    }
  }
  __syncthreads();

  // ---- MFMA: acc[p 64][h 128] over K=256, all frag reads lane-linear ----
  f32x4 acc[2][4] = {};
#pragma unroll
  for (int ks = 0; ks < 8; ++ks) {
    uint4 b01 = *reinterpret_cast<const uint4*>(sB + ((ks * 2 + 0) * 2 + wn) * 1024 + lane * 16);
    uint4 b23 = *reinterpret_cast<const uint4*>(sB + ((ks * 2 + 1) * 2 + wn) * 1024 + lane * 16);
    uint4 aa = *reinterpret_cast<const uint4*>(sF + ks * 2080 + wm * 1024 + lane * 16);
    long a0 = mk64(aa.x, aa.y), a1 = mk64(aa.z, aa.w);
    long bb0 = mk64(b01.x, b01.y), bb1 = mk64(b01.z, b01.w);
    long bb2 = mk64(b23.x, b23.y), bb3 = mk64(b23.z, b23.w);
    acc[0][0] = __builtin_amdgcn_mfma_f32_16x16x32_fp8_fp8(a0, bb0, acc[0][0], 0, 0, 0);
    acc[0][1] = __builtin_amdgcn_mfma_f32_16x16x32_fp8_fp8(a0, bb1, acc[0][1], 0, 0, 0);
    acc[0][2] = __builtin_amdgcn_mfma_f32_16x16x32_fp8_fp8(a0, bb2, acc[0][2], 0, 0, 0);
    acc[0][3] = __builtin_amdgcn_mfma_f32_16x16x32_fp8_fp8(a0, bb3, acc[0][3], 0, 0, 0);
    acc[1][0] = __builtin_amdgcn_mfma_f32_16x16x32_fp8_fp8(a1, bb0, acc[1][0], 0, 0, 0);
    acc[1][1] = __builtin_amdgcn_mfma_f32_16x16x32_fp8_fp8(a1, bb1, acc[1][1], 0, 0, 0);
    acc[1][2] = __builtin_amdgcn_mfma_f32_16x16x32_fp8_fp8(a1, bb2, acc[1][2], 0, 0, 0);
    acc[1][3] = __builtin_amdgcn_mfma_f32_16x16x32_fp8_fp8(a1, bb3, acc[1][3], 0, 0, 0);
  }

  __syncthreads();  // sF dead -> reuse as sPart
  float(*sPart)[33] = reinterpret_cast<float(*)[33]>(sF);

  // ---- epilogue: bias/scalar add, relu, dot W2 -> 32 partials per pair ----
#pragma unroll
  for (int mi = 0; mi < 2; ++mi) {
#pragma unroll
    for (int r = 0; r < 4; ++r) {
      int p = wm * 32 + mi * 16 + quad * 4 + r;  // C/D: row = quad*4 + reg
      float s0 = sScal[p][0], s1 = sScal[p][1], s2 = sScal[p][2], s3 = sScal[p][3];
      float val = 0.f;
#pragma unroll
      for (int ni = 0; ni < 4; ++ni) {
        float pre = fmaf(acc[mi][ni][r], INV256, cCi[ni]) + pj[mi][r][ni];
        pre = fmaf(s0, cB0[ni], pre);
        pre = fmaf(s1, cB1[ni], pre);
        pre = fmaf(s2, cB2[ni], pre);
        pre = fmaf(s3, cB3[ni], pre);
        val = fmaf(fmaxf(pre, 0.f), cW2[ni], val);
      }
      sPart[p][wn * 16 + col] = val;
    }
  }
  __syncthreads();
  if (tid < 64) {
    float s = b2v;
#pragma unroll
    for (int c = 0; c < 32; ++c) s += sPart[tid][c];
    int jg = j0 + tid;
    if (jg != i) {
      atomicAdd(out + (size_t)(b * 256 + i) * 256 + jg, 0.5f * s);
      atomicAdd(out + (size_t)(b * 256 + jg) * 256 + i, 0.5f * s);
    }
  }
}

extern "C" void kernel_launch(void* const* d_in, const int* in_sizes, int n_in,
                              void* d_out, int out_size, void* d_ws, size_t ws_size,
                              hipStream_t stream) {
  const float* node = (const float*)d_in[0];   // [4,256,128]
  const float* baseL = (const float*)d_in[1];  // [4,256,256]
  const float* compL = (const float*)d_in[2];  // [4,256,256]
  const float* W1 = (const float*)d_in[3];     // [516,128]
  const float* b1 = (const float*)d_in[4];     // [128]
  const float* W2 = (const float*)d_in[5];     // [128,1]
  const float* b2 = (const float*)d_in[6];     // [1]
  float* out = (float*)d_out;                  // [4,256,256] fp32

  char* ws = (char*)d_ws;
  float* PiB = (float*)(ws);                                  // 512 KB
  unsigned short* Pjh = (unsigned short*)(ws + (512 << 10));  // 256 KB
  uint32_t* W1f8 = (uint32_t*)(ws + (768 << 10));             // 32 KB

  pre_k<<<2080, 128, 0, stream>>>(node, W1, b1, PiB, Pjh, W1f8, out);
  main_k<<<4096, 256, 0, stream>>>(node, baseL, compL, W1, W2, b2, W1f8, PiB, Pjh, out);
}